// Round 1
// 340.980 us; speedup vs baseline: 1.0570x; 1.0570x over previous
//
#include <hip/hip_runtime.h>
#include <hip/hip_bf16.h>

using s8v   = __attribute__((ext_vector_type(8))) short;
using f32x4 = __attribute__((ext_vector_type(4))) float;

#define N_TOT 100352              // 32*56*56
#define WT_ELEMS 589824           // 36 K-tiles * 2048 units * 8 shorts
#define PLANE_ELEMS 861184        // 32*58*58*8 (one channel-group plane)
#define XT_ELEMS 27557888         // 32 planes
#define WS_NEED  56295424         // bytes: 2*(WT_ELEMS+XT_ELEMS)

__device__ __forceinline__ unsigned short f2bf(float f) {
    unsigned int u = __float_as_uint(f);
    unsigned int r = (u + 0x7FFF + ((u >> 16) & 1)) >> 16;  // RNE
    return (unsigned short)r;
}

__device__ __forceinline__ void gl_lds16(const void* g, void* l) {
    __builtin_amdgcn_global_load_lds(
        (const __attribute__((address_space(1))) unsigned int*)g,
        (__attribute__((address_space(3))) unsigned int*)l, 16, 0, 0);
}

// weights [O=256][C=256][9] fp32 -> wt: 36 K-tiles (BK=64 = ksteps 2t,2t+1; kstep=(cb,tap))
// Each tile = exact LDS image [row o=0..255][slot s=0..7] of 16B units, XOR-pre-swizzled:
// slot s of row o holds k-chunk ksub = s ^ (o&7); chunk ksub = (ks=ksub>>2, c2=ksub&3)
// = channels cb*32 + c2*8 .. +8 of tap(ks). gemm A-stage is then a pure linear copy.
__global__ void prep_w(const float* __restrict__ w, unsigned short* __restrict__ wt) {
    int u = blockIdx.x * 256 + threadIdx.x;   // 0..73727 16B-units
    int kt = u >> 11;
    int r  = u & 2047;
    int o  = r >> 3;
    int s  = r & 7;
    int ksub  = s ^ (o & 7);
    int kstep = kt * 2 + (ksub >> 2);
    int cb = kstep / 9, tap = kstep - cb * 9;
    int c0 = cb * 32 + (ksub & 3) * 8;
    const float* src = w + ((size_t)(o * 256 + c0)) * 9 + tap;
    unsigned int p[4];
    #pragma unroll
    for (int q = 0; q < 4; ++q) {
        float f0 = src[(2 * q) * 9];
        float f1 = src[(2 * q + 1) * 9];
        p[q] = (unsigned)f2bf(f0) | ((unsigned)f2bf(f1) << 16);
    }
    *(uint4*)(wt + (size_t)u * 8) = *(uint4*)p;
}

// x [32][256][56][56] fp32 -> Xt [cg=32][b=32][hp=58][wp=58][8ch] bf16, zero-padded.
// (unchanged from previous version)
__global__ void prep_x(const float* __restrict__ x, unsigned short* __restrict__ xt) {
    int b  = blockIdx.x / 58;
    int hp = blockIdx.x % 58;
    int tid = threadIdx.x;
    uint4 zero = {0u, 0u, 0u, 0u};
    size_t rowbase = (size_t)(b * 58 + hp) * 58;
    if (hp == 0 || hp == 57) {
        for (int i = tid; i < 1856; i += 256) {
            int cg = i / 58, wp = i - cg * 58;
            *(uint4*)(xt + ((size_t)cg * PLANE_ELEMS + (rowbase + wp) * 8)) = zero;
        }
        return;
    }
    int h = hp - 1;
    int wave = tid >> 6, lane = tid & 63;
    for (int cg = wave; cg < 32; cg += 4) {
        unsigned short* outp = xt + (size_t)cg * PLANE_ELEMS + rowbase * 8;
        if (lane < 56) {
            const float* src = x + ((size_t)(b * 256 + cg * 8) * 3136 + h * 56 + lane);
            unsigned int p[4];
            #pragma unroll
            for (int q = 0; q < 4; ++q) {
                float f0 = src[(size_t)(2 * q) * 3136];
                float f1 = src[(size_t)(2 * q + 1) * 3136];
                p[q] = (unsigned)f2bf(f0) | ((unsigned)f2bf(f1) << 16);
            }
            *(uint4*)(outp + (size_t)(lane + 1) * 8) = *(uint4*)p;
        } else if (lane == 56) {
            *(uint4*)outp = zero;
        } else if (lane == 57) {
            *(uint4*)(outp + 57 * 8) = zero;
        }
    }
}

// 256x256xBK64 implicit-GEMM conv, 8 waves (2M x 4N, per-wave 128x64), double-buffered
// 128 KiB LDS, depth-1 prefetch with counted vmcnt(8) (never drained in-loop), raw
// s_barrier (2 per K-tile), XOR-swizzled LDS (2-way = free), setprio around MFMA.
// K = 2304 = 36 tiles; kstep -> (cb,tap), B source = xt planes + tap shift.
__global__ __launch_bounds__(512, 2) void gemm8(const unsigned short* __restrict__ wt,
                                                const unsigned short* __restrict__ xt,
                                                float* __restrict__ out) {
    extern __shared__ char lds[];             // 131072 B: [buf 2][A 32768 | B 32768]
    int bx = blockIdx.x;
    int nt = (bx & 7) * 49 + (bx >> 3);       // 392 = 8*49: bijective XCD swizzle
    int tid  = threadIdx.x;
    int w    = tid >> 6, lane = tid & 63;
    int l16  = lane & 15, quad = lane >> 4;
    int wm   = w >> 2,   wn   = w & 3;

    // ---- B-stage per-lane constants: lane l writes LDS row r=(base + l>>3), slot s=l&7,
    // which must hold k-chunk ksub = s ^ (r&7) = (l&7) ^ (l>>3)  (it,w are multiples of 8)
    int ksub  = (lane & 7) ^ (lane >> 3);
    int ksl   = ksub >> 2;                    // which kstep of the tile (0/1)
    int c2off = (ksub & 3) * PLANE_ELEMS;     // plane within the 32-ch block
    int pixoff[4];
    #pragma unroll
    for (int it = 0; it < 4; ++it) {
        int n = nt * 256 + w * 32 + it * 8 + (lane >> 3);
        int b = n / 3136; int rr = n - b * 3136;
        int h = rr / 56;  int ww = rr - h * 56;
        pixoff[it] = ((b * 58 + h) * 58 + ww) * 8;   // padded-origin pixel, in shorts
    }

    // ---- ds_read per-lane bases: row*128 + (chunk ^ (row&7))*16, chunk = ks*4+quad
    int swz = (quad ^ (l16 & 7)) << 4;
    int aK0 = wm * 16384 + l16 * 128 + swz;
    int aK1 = aK0 ^ 64;                       // ks=1: chunk+4 == XOR 0x40 on swizzled slot
    int bK0 = 32768 + wn * 8192 + l16 * 128 + swz;
    int bK1 = bK0 ^ 64;

    auto STAGE = [&](char* buf, const unsigned short* aP, int bo0, int bo1) {
        // A: pure linear copy of the pre-swizzled 32 KiB tile
        #pragma unroll
        for (int it = 0; it < 4; ++it)
            gl_lds16(aP + it * 4096 + w * 512 + lane * 8, buf + it * 8192 + w * 1024);
        // B: per-lane inverse-swizzled gather from xt planes
        int bsel = (ksl ? bo1 : bo0) + c2off;
        #pragma unroll
        for (int it = 0; it < 4; ++it)
            gl_lds16(xt + (size_t)(unsigned)(bsel + pixoff[it]),
                     buf + 32768 + w * 4096 + it * 1024);
    };

    f32x4 acc[8][4] = {};

    // prologue: tile 0 = ksteps 0,1 -> (cb0,tap0)=(0,0) ts=0 ; (0,1) ts=1
    STAGE(lds, wt, 0, 1 * 8);
    const unsigned short* aP = wt + 16384;

    #pragma unroll 2
    for (int t = 0; t < 36; ++t) {
        if (t < 35) {
            int kk  = 2 * (t + 1);
            int cb0 = kk / 9,       tap0 = kk - cb0 * 9;
            int cb1 = (kk + 1) / 9, tap1 = (kk + 1) - cb1 * 9;
            int ts0 = (tap0 / 3) * 58 + tap0 - (tap0 / 3) * 3;
            int ts1 = (tap1 / 3) * 58 + tap1 - (tap1 / 3) * 3;
            STAGE(lds + ((t + 1) & 1) * 65536, aP,
                  cb0 * 4 * PLANE_ELEMS + ts0 * 8,
                  cb1 * 4 * PLANE_ELEMS + ts1 * 8);
            aP += 16384;
            asm volatile("s_waitcnt vmcnt(8)" ::: "memory");   // tile t landed; t+1 in flight
        } else {
            asm volatile("s_waitcnt vmcnt(0)" ::: "memory");
        }
        asm volatile("s_barrier" ::: "memory");
        const char* base = lds + (t & 1) * 65536;
        #pragma unroll
        for (int mh = 0; mh < 2; ++mh) {
            s8v af0[4], af1[4];
            #pragma unroll
            for (int f = 0; f < 4; ++f) {
                af0[f] = *(const s8v*)(base + aK0 + (mh * 4 + f) * 2048);
                af1[f] = *(const s8v*)(base + aK1 + (mh * 4 + f) * 2048);
            }
            #pragma unroll
            for (int nh = 0; nh < 2; ++nh) {
                s8v bf0[2], bf1[2];
                #pragma unroll
                for (int g = 0; g < 2; ++g) {
                    bf0[g] = *(const s8v*)(base + bK0 + (nh * 2 + g) * 2048);
                    bf1[g] = *(const s8v*)(base + bK1 + (nh * 2 + g) * 2048);
                }
                __builtin_amdgcn_s_setprio(1);
                #pragma unroll
                for (int f = 0; f < 4; ++f)
                    #pragma unroll
                    for (int g = 0; g < 2; ++g) {
                        f32x4 c = acc[mh * 4 + f][nh * 2 + g];
                        c = __builtin_amdgcn_mfma_f32_16x16x32_bf16(af0[f], bf0[g], c, 0, 0, 0);
                        c = __builtin_amdgcn_mfma_f32_16x16x32_bf16(af1[f], bf1[g], c, 0, 0, 0);
                        acc[mh * 4 + f][nh * 2 + g] = c;
                    }
                __builtin_amdgcn_s_setprio(0);
            }
        }
        asm volatile("s_barrier" ::: "memory");   // all reads of buf done -> next overwrite safe
    }

    // Epilogue: C/D layout col=l16 (n), row=quad*4+reg (m=o). out is [O][N_TOT].
    float* op = out + (size_t)(wm * 128 + quad * 4) * N_TOT + nt * 256 + wn * 64 + l16;
    #pragma unroll
    for (int f = 0; f < 8; ++f)
        #pragma unroll
        for (int rr = 0; rr < 4; ++rr) {
            float* orow = op + (size_t)(f * 16 + rr) * N_TOT;
            #pragma unroll
            for (int g = 0; g < 4; ++g)
                orow[g * 16] = acc[f][g][rr];
        }
}

// Fallback if workspace too small: direct conv, one thread per output.
__global__ void conv_naive(const float* __restrict__ x, const float* __restrict__ wq,
                           float* __restrict__ out) {
    int f = blockIdx.x * 256 + threadIdx.x;
    int o = f / N_TOT;
    int n = f - o * N_TOT;
    int b = n / 3136; int r = n - b * 3136; int h = r / 56; int w = r - h * 56;
    const float* xb = x + (size_t)b * 256 * 3136;
    const float* wo = wq + o * 2304;
    float acc = 0.f;
    for (int c = 0; c < 256; ++c) {
        const float* xc = xb + c * 3136;
        const float* wc = wo + c * 9;
        #pragma unroll
        for (int dh = 0; dh < 3; ++dh) {
            int ih = h + dh - 1;
            if (ih < 0 || ih >= 56) continue;
            const float* xr = xc + ih * 56;
            #pragma unroll
            for (int dw = 0; dw < 3; ++dw) {
                int iw = w + dw - 1;
                if (iw >= 0 && iw < 56) acc += xr[iw] * wc[dh * 3 + dw];
            }
        }
    }
    out[f] = acc;
}

extern "C" void kernel_launch(void* const* d_in, const int* in_sizes, int n_in,
                              void* d_out, int out_size, void* d_ws, size_t ws_size,
                              hipStream_t stream) {
    const float* x = (const float*)d_in[0];
    const float* w = (const float*)d_in[1];
    float* out = (float*)d_out;
    if (ws_size >= (size_t)WS_NEED) {
        unsigned short* wt = (unsigned short*)d_ws;
        unsigned short* xt = wt + WT_ELEMS;
        static int attr_done = 0;
        if (!attr_done) {
            hipFuncSetAttribute((const void*)gemm8,
                                hipFuncAttributeMaxDynamicSharedMemorySize, 131072);
            attr_done = 1;
        }
        prep_w<<<288, 256, 0, stream>>>(w, wt);
        prep_x<<<32 * 58, 256, 0, stream>>>(x, xt);
        gemm8<<<392, 512, 131072, stream>>>(wt, xt, out);
    } else {
        conv_naive<<<N_TOT, 256, 0, stream>>>(x, w, out);
    }
}

// Round 2
// 328.683 us; speedup vs baseline: 1.0966x; 1.0374x over previous
//
#include <hip/hip_runtime.h>
#include <hip/hip_bf16.h>

using s8v   = __attribute__((ext_vector_type(8))) short;
using f32x4 = __attribute__((ext_vector_type(4))) float;

#define N_TOT 100352              // 32*56*56
#define WT_ELEMS 589824           // 36 K-tiles * 2048 units * 8 shorts
#define PLANE_ELEMS 861184        // 32*58*58*8 (one channel-group plane)
#define XT_ELEMS 27557888         // 32 planes
#define WS_NEED  56295424         // bytes: 2*(WT_ELEMS+XT_ELEMS)

#define BAR() asm volatile("s_barrier" ::: "memory")

__device__ __forceinline__ unsigned short f2bf(float f) {
    unsigned int u = __float_as_uint(f);
    unsigned int r = (u + 0x7FFF + ((u >> 16) & 1)) >> 16;  // RNE
    return (unsigned short)r;
}

__device__ __forceinline__ void gl_lds16(const void* g, void* l) {
    __builtin_amdgcn_global_load_lds(
        (const __attribute__((address_space(1))) unsigned int*)g,
        (__attribute__((address_space(3))) unsigned int*)l, 16, 0, 0);
}

// weights [O=256][C=256][9] fp32 -> wt: 36 K-tiles (BK=64 = ksteps 2t,2t+1)
// Tile = exact LDS image [row o=0..255][slot s=0..7] of 16B units, XOR-pre-swizzled:
// slot s of row o holds k-chunk ksub = s ^ (o&7); ksub=(ks<<2)|c2 -> kstep 2t+ks,
// channels cb*32 + c2*8 .. +8. gemm A-stage is a pure linear copy.
__global__ void prep_w(const float* __restrict__ w, unsigned short* __restrict__ wt) {
    int u = blockIdx.x * 256 + threadIdx.x;   // 0..73727 16B-units
    int kt = u >> 11;
    int r  = u & 2047;
    int o  = r >> 3;
    int s  = r & 7;
    int ksub  = s ^ (o & 7);
    int kstep = kt * 2 + (ksub >> 2);
    int cb = kstep / 9, tap = kstep - cb * 9;
    int c0 = cb * 32 + (ksub & 3) * 8;
    const float* src = w + ((size_t)(o * 256 + c0)) * 9 + tap;
    unsigned int p[4];
    #pragma unroll
    for (int q = 0; q < 4; ++q) {
        float f0 = src[(2 * q) * 9];
        float f1 = src[(2 * q + 1) * 9];
        p[q] = (unsigned)f2bf(f0) | ((unsigned)f2bf(f1) << 16);
    }
    *(uint4*)(wt + (size_t)u * 8) = *(uint4*)p;
}

// x [32][256][56][56] fp32 -> Xt [cg=32][b=32][hp=58][wp=58][8ch] bf16, zero-padded.
__global__ void prep_x(const float* __restrict__ x, unsigned short* __restrict__ xt) {
    int b  = blockIdx.x / 58;
    int hp = blockIdx.x % 58;
    int tid = threadIdx.x;
    uint4 zero = {0u, 0u, 0u, 0u};
    size_t rowbase = (size_t)(b * 58 + hp) * 58;
    if (hp == 0 || hp == 57) {
        for (int i = tid; i < 1856; i += 256) {
            int cg = i / 58, wp = i - cg * 58;
            *(uint4*)(xt + ((size_t)cg * PLANE_ELEMS + (rowbase + wp) * 8)) = zero;
        }
        return;
    }
    int h = hp - 1;
    int wave = tid >> 6, lane = tid & 63;
    for (int cg = wave; cg < 32; cg += 4) {
        unsigned short* outp = xt + (size_t)cg * PLANE_ELEMS + rowbase * 8;
        if (lane < 56) {
            const float* src = x + ((size_t)(b * 256 + cg * 8) * 3136 + h * 56 + lane);
            unsigned int p[4];
            #pragma unroll
            for (int q = 0; q < 4; ++q) {
                float f0 = src[(size_t)(2 * q) * 3136];
                float f1 = src[(size_t)(2 * q + 1) * 3136];
                p[q] = (unsigned)f2bf(f0) | ((unsigned)f2bf(f1) << 16);
            }
            *(uint4*)(outp + (size_t)(lane + 1) * 8) = *(uint4*)p;
        } else if (lane == 56) {
            *(uint4*)outp = zero;
        } else if (lane == 57) {
            *(uint4*)(outp + 57 * 8) = zero;
        }
    }
}

// 256x256xBK64 implicit-GEMM conv, m201 8-phase schedule (4 phases/K-tile):
// per phase {ds_read quadrant frags | stage 1 half-tile | s_barrier | 16 MFMA | s_barrier},
// vmcnt(6) only at P3 (3 half-tiles in flight, never drained in-loop).
// Half-tile staging into regions dead since the last barrier:
//  t.P0 -> (t+1, A-mh1) [other buf]   t.P1 -> (t+2, A-mh0) [this buf, read at P0]
//  t.P2 -> (t+2, B-nh0) [read at P0]  t.P3 -> (t+2, B-nh1) [read at P1]
__global__ __launch_bounds__(512, 2) void gemm8(const unsigned short* __restrict__ wt,
                                                const unsigned short* __restrict__ xt,
                                                float* __restrict__ out) {
    extern __shared__ char lds[];             // 131072 B: [buf 2][A 32768 | B 32768]
    int bx = blockIdx.x;
    int nt = (bx & 7) * 49 + (bx >> 3);       // 392 = 8*49: bijective XCD swizzle
    int tid  = threadIdx.x;
    int w    = tid >> 6, lane = tid & 63;
    int l16  = lane & 15, quad = lane >> 4;
    int wm   = w >> 2,   wn   = w & 3;
    int lane16 = lane * 16;

    // ---- staging constants. slots s = w*2+it (it=0,1), 16 slots x 8 rows/pixels.
    // A half-tile (mh stripe): rows {0-63,128-191} (+64 for mh1). dest uniform base:
    int s0 = w * 2, s1 = w * 2 + 1;
    int adst0 = ((s0 >> 3) * 128 + (s0 & 7) * 8) * 128;
    int adst1 = ((s1 >> 3) * 128 + (s1 & 7) * 8) * 128;
    // B half-tile (nh stripe): pixels {0-31,64-95,128-159,192-223} (+32 for nh1)
    int bp0 = ((s0 >> 2) * 64 + (s0 & 3) * 8);
    int bp1 = ((s1 >> 2) * 64 + (s1 & 3) * 8);
    int bdst0 = bp0 * 128;
    int bdst1 = bp1 * 128;
    // per-lane k-chunk for B gather: lane l supplies slot l&7 of row base+(l>>3)
    int ksub  = (lane & 7) ^ (lane >> 3);
    int ksl   = ksub >> 2;
    int c2off = (ksub & 3) * PLANE_ELEMS;
    // padded-pixel offsets (shorts) for the 4 (it,h) staging targets
    int pix[2][2];
    #pragma unroll
    for (int it = 0; it < 2; ++it)
        #pragma unroll
        for (int h = 0; h < 2; ++h) {
            int n = nt * 256 + (it ? bp1 : bp0) + h * 32 + (lane >> 3);
            int b = n / 3136; int rr = n - b * 3136;
            int hh = rr / 56; int ww = rr - hh * 56;
            pix[it][h] = ((b * 58 + hh) * 58 + ww) * 8;
        }
    int pix00 = pix[0][0], pix01 = pix[0][1], pix10 = pix[1][0], pix11 = pix[1][1];

    // ---- ds_read per-lane bases: row*128 + (chunk ^ (row&7))*16, chunk = ks*4+quad
    int swz = (quad ^ (l16 & 7)) << 4;
    int aK0 = wm * 16384 + l16 * 128 + swz;
    int aK1 = aK0 ^ 64;
    int bK0 = 32768 + wn * 8192 + l16 * 128 + swz;
    int bK1 = bK0 ^ 64;

    auto SA = [&](char* buf, const char* srcTile, int roff) {
        gl_lds16(srcTile + adst0 + roff + lane16, buf + adst0 + roff);
        gl_lds16(srcTile + adst1 + roff + lane16, buf + adst1 + roff);
    };
    auto SB = [&](char* buf, int bo0, int bo1, int h) {
        int bsel = (ksl ? bo1 : bo0) + c2off;
        gl_lds16(xt + (size_t)(unsigned)(bsel + (h ? pix01 : pix00)),
                 buf + 32768 + bdst0 + h * 4096);
        gl_lds16(xt + (size_t)(unsigned)(bsel + (h ? pix11 : pix10)),
                 buf + 32768 + bdst1 + h * 4096);
    };
    auto BO = [&](int ks) {
        int cb = ks / 9, tap = ks - cb * 9;
        return cb * 4 * PLANE_ELEMS + ((tap / 3) * 58 + (tap - (tap / 3) * 3)) * 8;
    };

    f32x4 acc[8][4] = {};
    s8v a0[4], a1[4], b00[2], b01[2], b10[2], b11[2];

    // ---- prologue: tile0 full, tile1 {A0,B0,B1}; 3 half-tiles left in flight
    SA(lds, (const char*)wt, 0);
    SA(lds, (const char*)wt, 8192);
    SB(lds, BO(0), BO(1), 0);
    SB(lds, BO(0), BO(1), 1);
    SA(lds + 65536, (const char*)wt + 32768, 0);
    SB(lds + 65536, BO(2), BO(3), 0);
    SB(lds + 65536, BO(2), BO(3), 1);
    asm volatile("s_waitcnt vmcnt(6)" ::: "memory");
    BAR();

    #define PHASE_MFMA(MH, NH, BA, BB)                                             \
        __builtin_amdgcn_s_setprio(1);                                             \
        _Pragma("unroll")                                                          \
        for (int f = 0; f < 4; ++f) {                                              \
            _Pragma("unroll")                                                      \
            for (int g = 0; g < 2; ++g) {                                          \
                f32x4 c = acc[(MH)*4 + f][(NH)*2 + g];                             \
                c = __builtin_amdgcn_mfma_f32_16x16x32_bf16(a0[f], BA[g], c, 0, 0, 0); \
                c = __builtin_amdgcn_mfma_f32_16x16x32_bf16(a1[f], BB[g], c, 0, 0, 0); \
                acc[(MH)*4 + f][(NH)*2 + g] = c;                                   \
            }                                                                      \
        }                                                                          \
        __builtin_amdgcn_s_setprio(0);

    #pragma unroll 1
    for (int t = 0; t < 36; ++t) {
        char* bufc = lds + (t & 1) * 65536;
        char* bufo = lds + ((t & 1) ^ 1) * 65536;
        const char* wA1 = (const char*)wt + (size_t)(t + 1) * 32768;
        const char* wA0 = (const char*)wt + (size_t)(t + 2) * 32768;
        int kk  = 2 * (t + 2);
        int bo0 = BO(kk);
        int bo1 = BO(kk + 1);

        // ---- P0: read (mh0, nh0) frags + both B nh0 halves' k pair; stage (t+1,A-mh1)
        #pragma unroll
        for (int f = 0; f < 4; ++f) {
            a0[f] = *(const s8v*)(bufc + aK0 + f * 2048);
            a1[f] = *(const s8v*)(bufc + aK1 + f * 2048);
        }
        #pragma unroll
        for (int g = 0; g < 2; ++g) {
            b00[g] = *(const s8v*)(bufc + bK0 + g * 2048);
            b01[g] = *(const s8v*)(bufc + bK1 + g * 2048);
        }
        if (t < 35) SA(bufo, wA1, 8192);
        BAR();
        PHASE_MFMA(0, 0, b00, b01)
        BAR();

        // ---- P1: read B nh1; stage (t+2, A-mh0) into this buf (region dead since P0)
        #pragma unroll
        for (int g = 0; g < 2; ++g) {
            b10[g] = *(const s8v*)(bufc + bK0 + 4096 + g * 2048);
            b11[g] = *(const s8v*)(bufc + bK1 + 4096 + g * 2048);
        }
        if (t < 34) SA(bufc, wA0, 0);
        BAR();
        PHASE_MFMA(0, 1, b10, b11)
        BAR();

        // ---- P2: read A mh1; stage (t+2, B-nh0) (dead since P0)
        #pragma unroll
        for (int f = 0; f < 4; ++f) {
            a0[f] = *(const s8v*)(bufc + aK0 + 8192 + f * 2048);
            a1[f] = *(const s8v*)(bufc + aK1 + 8192 + f * 2048);
        }
        if (t < 34) SB(bufc, bo0, bo1, 0);
        BAR();
        PHASE_MFMA(1, 0, b00, b01)
        BAR();

        // ---- P3: stage (t+2, B-nh1) (dead since P1); counted gate; no ds_reads
        if (t < 34) {
            SB(bufc, bo0, bo1, 1);
            asm volatile("s_waitcnt vmcnt(6)" ::: "memory");
        } else if (t == 34) {
            asm volatile("s_waitcnt vmcnt(0)" ::: "memory");
        }
        BAR();
        PHASE_MFMA(1, 1, b10, b11)
        BAR();
    }

    // Epilogue: C/D layout col=l16 (n), row=quad*4+reg (m=o). out is [O][N_TOT].
    float* op = out + (size_t)(wm * 128 + quad * 4) * N_TOT + nt * 256 + wn * 64 + l16;
    #pragma unroll
    for (int f = 0; f < 8; ++f)
        #pragma unroll
        for (int rr = 0; rr < 4; ++rr) {
            float* orow = op + (size_t)(f * 16 + rr) * N_TOT;
            #pragma unroll
            for (int g = 0; g < 4; ++g)
                orow[g * 16] = acc[f][g][rr];
        }
}

// Fallback if workspace too small: direct conv, one thread per output.
__global__ void conv_naive(const float* __restrict__ x, const float* __restrict__ wq,
                           float* __restrict__ out) {
    int f = blockIdx.x * 256 + threadIdx.x;
    int o = f / N_TOT;
    int n = f - o * N_TOT;
    int b = n / 3136; int r = n - b * 3136; int h = r / 56; int w = r - h * 56;
    const float* xb = x + (size_t)b * 256 * 3136;
    const float* wo = wq + o * 2304;
    float acc = 0.f;
    for (int c = 0; c < 256; ++c) {
        const float* xc = xb + c * 3136;
        const float* wc = wo + c * 9;
        #pragma unroll
        for (int dh = 0; dh < 3; ++dh) {
            int ih = h + dh - 1;
            if (ih < 0 || ih >= 56) continue;
            const float* xr = xc + ih * 56;
            #pragma unroll
            for (int dw = 0; dw < 3; ++dw) {
                int iw = w + dw - 1;
                if (iw >= 0 && iw < 56) acc += xr[iw] * wc[dh * 3 + dw];
            }
        }
    }
    out[f] = acc;
}

extern "C" void kernel_launch(void* const* d_in, const int* in_sizes, int n_in,
                              void* d_out, int out_size, void* d_ws, size_t ws_size,
                              hipStream_t stream) {
    const float* x = (const float*)d_in[0];
    const float* w = (const float*)d_in[1];
    float* out = (float*)d_out;
    if (ws_size >= (size_t)WS_NEED) {
        unsigned short* wt = (unsigned short*)d_ws;
        unsigned short* xt = wt + WT_ELEMS;
        static int attr_done = 0;
        if (!attr_done) {
            hipFuncSetAttribute((const void*)gemm8,
                                hipFuncAttributeMaxDynamicSharedMemorySize, 131072);
            attr_done = 1;
        }
        prep_w<<<288, 256, 0, stream>>>(w, wt);
        prep_x<<<32 * 58, 256, 0, stream>>>(x, xt);
        gemm8<<<392, 512, 131072, stream>>>(wt, xt, out);
    } else {
        conv_naive<<<N_TOT, 256, 0, stream>>>(x, w, out);
    }
}

// Round 3
// 321.216 us; speedup vs baseline: 1.1221x; 1.0232x over previous
//
#include <hip/hip_runtime.h>
#include <hip/hip_bf16.h>

using s8v   = __attribute__((ext_vector_type(8))) short;
using f32x4 = __attribute__((ext_vector_type(4))) float;

#define N_TOT 100352              // 32*56*56
#define WT_ELEMS 589824           // 36 K-tiles * 2048 units * 8 shorts
#define PLANE_ELEMS 861184        // 32*58*58*8 (one channel-group plane)
#define XT_ELEMS 27557888         // 32 planes
#define WS_NEED  56295424         // bytes: 2*(WT_ELEMS+XT_ELEMS)

#define BAR() asm volatile("s_barrier" ::: "memory")
#define GATE(T) do { if ((T) < 33) asm volatile("s_waitcnt vmcnt(8)" ::: "memory"); \
                     else          asm volatile("s_waitcnt vmcnt(0)" ::: "memory"); } while (0)

__device__ __forceinline__ unsigned short f2bf(float f) {
    unsigned int u = __float_as_uint(f);
    unsigned int r = (u + 0x7FFF + ((u >> 16) & 1)) >> 16;  // RNE
    return (unsigned short)r;
}

__device__ __forceinline__ void gl_lds16(const void* g, void* l) {
    __builtin_amdgcn_global_load_lds(
        (const __attribute__((address_space(1))) unsigned int*)g,
        (__attribute__((address_space(3))) unsigned int*)l, 16, 0, 0);
}

// weights [O=256][C=256][9] fp32 -> wt: 36 K-tiles (BK=64 = ksteps 2t,2t+1)
// Tile = exact LDS image [row o=0..255][slot s=0..7] of 16B units, XOR-pre-swizzled:
// slot s of row o holds k-chunk ksub = s ^ (o&7); ksub=(ks<<2)|c2 -> kstep 2t+ks,
// channels cb*32 + c2*8 .. +8. gemm A-stage is a pure linear copy.
__global__ void prep_w(const float* __restrict__ w, unsigned short* __restrict__ wt) {
    int u = blockIdx.x * 256 + threadIdx.x;   // 0..73727 16B-units
    int kt = u >> 11;
    int r  = u & 2047;
    int o  = r >> 3;
    int s  = r & 7;
    int ksub  = s ^ (o & 7);
    int kstep = kt * 2 + (ksub >> 2);
    int cb = kstep / 9, tap = kstep - cb * 9;
    int c0 = cb * 32 + (ksub & 3) * 8;
    const float* src = w + ((size_t)(o * 256 + c0)) * 9 + tap;
    unsigned int p[4];
    #pragma unroll
    for (int q = 0; q < 4; ++q) {
        float f0 = src[(2 * q) * 9];
        float f1 = src[(2 * q + 1) * 9];
        p[q] = (unsigned)f2bf(f0) | ((unsigned)f2bf(f1) << 16);
    }
    *(uint4*)(wt + (size_t)u * 8) = *(uint4*)p;
}

// x [32][256][56][56] fp32 -> Xt [cg=32][b=32][hp=58][wp=58][8ch] bf16, zero-padded.
__global__ void prep_x(const float* __restrict__ x, unsigned short* __restrict__ xt) {
    int b  = blockIdx.x / 58;
    int hp = blockIdx.x % 58;
    int tid = threadIdx.x;
    uint4 zero = {0u, 0u, 0u, 0u};
    size_t rowbase = (size_t)(b * 58 + hp) * 58;
    if (hp == 0 || hp == 57) {
        for (int i = tid; i < 1856; i += 256) {
            int cg = i / 58, wp = i - cg * 58;
            *(uint4*)(xt + ((size_t)cg * PLANE_ELEMS + (rowbase + wp) * 8)) = zero;
        }
        return;
    }
    int h = hp - 1;
    int wave = tid >> 6, lane = tid & 63;
    for (int cg = wave; cg < 32; cg += 4) {
        unsigned short* outp = xt + (size_t)cg * PLANE_ELEMS + rowbase * 8;
        if (lane < 56) {
            const float* src = x + ((size_t)(b * 256 + cg * 8) * 3136 + h * 56 + lane);
            unsigned int p[4];
            #pragma unroll
            for (int q = 0; q < 4; ++q) {
                float f0 = src[(size_t)(2 * q) * 3136];
                float f1 = src[(size_t)(2 * q + 1) * 3136];
                p[q] = (unsigned)f2bf(f0) | ((unsigned)f2bf(f1) << 16);
            }
            *(uint4*)(outp + (size_t)(lane + 1) * 8) = *(uint4*)p;
        } else if (lane == 56) {
            *(uint4*)outp = zero;
        } else if (lane == 57) {
            *(uint4*)(outp + 57 * 8) = zero;
        }
    }
}

// 256x256xBK64 implicit-GEMM conv. ONE barrier per phase; each phase:
//   { BAR; ds_read NEXT consumer's frags; stage 1 half-tile; MFMA on regs read
//     a phase earlier; vmcnt(8) }
// so LDS reads overlap MFMA. vmcnt(8) = last 4 phases' stages in flight; each
// gate drains exactly the stage issued 4 phases ago (the one the next read needs).
// Read rotation:  P0: bO(t)   P1: aO-ks0(t)   P2: aO-ks1(t) + aE-ks0(t+1)
//                 P3: aE-ks1(t+1) + bE(t+1)
// Stage rotation: P0:(t+1,A-mh1)  P1:(t+2,A-mh0)  P2:(t+2,B-nh0)  P3:(t+2,B-nh1)
// Every staged region's last reader finished >=2 barriers before the write issues.
__global__ __launch_bounds__(512, 2) void gemm8(const unsigned short* __restrict__ wt,
                                                const unsigned short* __restrict__ xt,
                                                float* __restrict__ out) {
    extern __shared__ char lds[];             // 131072 B: [buf 2][A 32768 | B 32768]
    int bx = blockIdx.x;
    int nt = (bx & 7) * 49 + (bx >> 3);       // 392 = 8*49: bijective XCD swizzle
    int tid  = threadIdx.x;
    int w    = tid >> 6, lane = tid & 63;
    int l16  = lane & 15, quad = lane >> 4;
    int wm   = w >> 2,   wn   = w & 3;
    int lane16 = lane * 16;

    // ---- staging constants. slots s = w*2+it (it=0,1), 16 slots x 8 rows/pixels.
    int s0 = w * 2, s1 = w * 2 + 1;
    int adst0 = ((s0 >> 3) * 128 + (s0 & 7) * 8) * 128;
    int adst1 = ((s1 >> 3) * 128 + (s1 & 7) * 8) * 128;
    int bp0 = ((s0 >> 2) * 64 + (s0 & 3) * 8);
    int bp1 = ((s1 >> 2) * 64 + (s1 & 3) * 8);
    int bdst0 = bp0 * 128;
    int bdst1 = bp1 * 128;
    // per-lane k-chunk for B gather: lane l supplies slot l&7 of row base+(l>>3)
    int ksub  = (lane & 7) ^ (lane >> 3);
    int ksl   = ksub >> 2;
    int c2off = (ksub & 3) * PLANE_ELEMS;
    int pix[2][2];
    #pragma unroll
    for (int it = 0; it < 2; ++it)
        #pragma unroll
        for (int h = 0; h < 2; ++h) {
            int n = nt * 256 + (it ? bp1 : bp0) + h * 32 + (lane >> 3);
            int b = n / 3136; int rr = n - b * 3136;
            int hh = rr / 56; int ww = rr - hh * 56;
            pix[it][h] = ((b * 58 + hh) * 58 + ww) * 8;
        }
    int pix00 = pix[0][0], pix01 = pix[0][1], pix10 = pix[1][0], pix11 = pix[1][1];

    // ---- ds_read per-lane bases: row*128 + (chunk ^ (row&7))*16, chunk = ks*4+quad
    int swz = (quad ^ (l16 & 7)) << 4;
    int aK0 = wm * 16384 + l16 * 128 + swz;
    int aK1 = aK0 ^ 64;
    int bK0 = 32768 + wn * 8192 + l16 * 128 + swz;
    int bK1 = bK0 ^ 64;

    auto SA = [&](char* buf, const char* srcTile, int roff) {
        gl_lds16(srcTile + adst0 + roff + lane16, buf + adst0 + roff);
        gl_lds16(srcTile + adst1 + roff + lane16, buf + adst1 + roff);
    };
    auto SB = [&](char* buf, int bo0, int bo1, int h) {
        int bsel = (ksl ? bo1 : bo0) + c2off;
        gl_lds16(xt + (size_t)(unsigned)(bsel + (h ? pix01 : pix00)),
                 buf + 32768 + bdst0 + h * 4096);
        gl_lds16(xt + (size_t)(unsigned)(bsel + (h ? pix11 : pix10)),
                 buf + 32768 + bdst1 + h * 4096);
    };
    auto BO = [&](int ks) {
        int cb = ks / 9, tap = ks - cb * 9;
        return cb * 4 * PLANE_ELEMS + ((tap / 3) * 58 + (tap - (tap / 3) * 3)) * 8;
    };

    f32x4 acc[8][4] = {};
    s8v aE0[4], aE1[4], aO0[4], aO1[4];
    s8v bE0[2], bE1[2], bO0[2], bO1[2];

    #define MFMA_Q(MH, NH, A0, A1, B0, B1)                                         \
        __builtin_amdgcn_s_setprio(1);                                             \
        _Pragma("unroll")                                                          \
        for (int f = 0; f < 4; ++f) {                                              \
            _Pragma("unroll")                                                      \
            for (int g = 0; g < 2; ++g)                                            \
                acc[(MH)*4+f][(NH)*2+g] = __builtin_amdgcn_mfma_f32_16x16x32_bf16( \
                    A0[f], B0[g], acc[(MH)*4+f][(NH)*2+g], 0, 0, 0);               \
        }                                                                          \
        _Pragma("unroll")                                                          \
        for (int f = 0; f < 4; ++f) {                                              \
            _Pragma("unroll")                                                      \
            for (int g = 0; g < 2; ++g)                                            \
                acc[(MH)*4+f][(NH)*2+g] = __builtin_amdgcn_mfma_f32_16x16x32_bf16( \
                    A1[f], B1[g], acc[(MH)*4+f][(NH)*2+g], 0, 0, 0);               \
        }                                                                          \
        __builtin_amdgcn_s_setprio(0);

    // ---- prologue: tile0 full; tile1 {A-mh0, B-nh0, B-nh1} (= virtual t-1 stages)
    SA(lds, (const char*)wt, 0);
    SA(lds, (const char*)wt, 8192);
    SB(lds, BO(0), BO(1), 0);
    SB(lds, BO(0), BO(1), 1);
    SA(lds + 65536, (const char*)wt + 32768, 0);
    SB(lds + 65536, BO(2), BO(3), 0);
    SB(lds + 65536, BO(2), BO(3), 1);
    asm volatile("s_waitcnt vmcnt(6)" ::: "memory");   // tile0 landed; tile1's 6 in flight
    BAR();
    // pre-read aE(0), bE(0)
    #pragma unroll
    for (int f = 0; f < 4; ++f) {
        aE0[f] = *(const s8v*)(lds + aK0 + f * 2048);
        aE1[f] = *(const s8v*)(lds + aK1 + f * 2048);
    }
    #pragma unroll
    for (int g = 0; g < 2; ++g) {
        bE0[g] = *(const s8v*)(lds + bK0 + g * 2048);
        bE1[g] = *(const s8v*)(lds + bK1 + g * 2048);
    }

    #pragma unroll 1
    for (int t = 0; t < 36; ++t) {
        char* bufc = lds + (t & 1) * 65536;
        char* bufo = lds + ((t & 1) ^ 1) * 65536;
        const char* wA1 = (const char*)wt + (size_t)(t + 1) * 32768;
        const char* wA0 = (const char*)wt + (size_t)(t + 2) * 32768;
        int kk  = 2 * (t + 2);
        int bo0 = BO(kk);
        int bo1 = BO(kk + 1);

        // ---- P0: read bO(t); stage (t+1,A-mh1); MFMA q00 (aE,bE)
        BAR();
        #pragma unroll
        for (int g = 0; g < 2; ++g) {
            bO0[g] = *(const s8v*)(bufc + bK0 + 4096 + g * 2048);
            bO1[g] = *(const s8v*)(bufc + bK1 + 4096 + g * 2048);
        }
        if (t < 35) SA(bufo, wA1, 8192);
        MFMA_Q(0, 0, aE0, aE1, bE0, bE1)
        GATE(t);

        // ---- P1: read aO-ks0(t); stage (t+2,A-mh0); MFMA q01 (aE,bO)
        BAR();
        #pragma unroll
        for (int f = 0; f < 4; ++f)
            aO0[f] = *(const s8v*)(bufc + aK0 + 8192 + f * 2048);
        if (t < 34) SA(bufc, wA0, 0);
        MFMA_Q(0, 1, aE0, aE1, bO0, bO1)
        GATE(t);

        // ---- P2: read aO-ks1(t) + aE-ks0(t+1); stage (t+2,B-nh0); MFMA q10 (aO,bE)
        BAR();
        #pragma unroll
        for (int f = 0; f < 4; ++f)
            aO1[f] = *(const s8v*)(bufc + aK1 + 8192 + f * 2048);
        if (t < 35) {
            #pragma unroll
            for (int f = 0; f < 4; ++f)
                aE0[f] = *(const s8v*)(bufo + aK0 + f * 2048);
        }
        if (t < 34) SB(bufc, bo0, bo1, 0);
        MFMA_Q(1, 0, aO0, aO1, bE0, bE1)
        GATE(t);

        // ---- P3: read aE-ks1(t+1) + bE(t+1); stage (t+2,B-nh1); MFMA q11 (aO,bO)
        BAR();
        if (t < 35) {
            #pragma unroll
            for (int f = 0; f < 4; ++f)
                aE1[f] = *(const s8v*)(bufo + aK1 + f * 2048);
            #pragma unroll
            for (int g = 0; g < 2; ++g) {
                bE0[g] = *(const s8v*)(bufo + bK0 + g * 2048);
                bE1[g] = *(const s8v*)(bufo + bK1 + g * 2048);
            }
        }
        if (t < 34) SB(bufc, bo0, bo1, 1);
        MFMA_Q(1, 1, aO0, aO1, bO0, bO1)
        GATE(t);
    }

    // Epilogue: C/D layout col=l16 (n), row=quad*4+reg (m=o). out is [O][N_TOT].
    float* op = out + (size_t)(wm * 128 + quad * 4) * N_TOT + nt * 256 + wn * 64 + l16;
    #pragma unroll
    for (int f = 0; f < 8; ++f)
        #pragma unroll
        for (int rr = 0; rr < 4; ++rr) {
            float* orow = op + (size_t)(f * 16 + rr) * N_TOT;
            #pragma unroll
            for (int g = 0; g < 4; ++g)
                orow[g * 16] = acc[f][g][rr];
        }
}

// Fallback if workspace too small: direct conv, one thread per output.
__global__ void conv_naive(const float* __restrict__ x, const float* __restrict__ wq,
                           float* __restrict__ out) {
    int f = blockIdx.x * 256 + threadIdx.x;
    int o = f / N_TOT;
    int n = f - o * N_TOT;
    int b = n / 3136; int r = n - b * 3136; int h = r / 56; int w = r - h * 56;
    const float* xb = x + (size_t)b * 256 * 3136;
    const float* wo = wq + o * 2304;
    float acc = 0.f;
    for (int c = 0; c < 256; ++c) {
        const float* xc = xb + c * 3136;
        const float* wc = wo + c * 9;
        #pragma unroll
        for (int dh = 0; dh < 3; ++dh) {
            int ih = h + dh - 1;
            if (ih < 0 || ih >= 56) continue;
            const float* xr = xc + ih * 56;
            #pragma unroll
            for (int dw = 0; dw < 3; ++dw) {
                int iw = w + dw - 1;
                if (iw >= 0 && iw < 56) acc += xr[iw] * wc[dh * 3 + dw];
            }
        }
    }
    out[f] = acc;
}

extern "C" void kernel_launch(void* const* d_in, const int* in_sizes, int n_in,
                              void* d_out, int out_size, void* d_ws, size_t ws_size,
                              hipStream_t stream) {
    const float* x = (const float*)d_in[0];
    const float* w = (const float*)d_in[1];
    float* out = (float*)d_out;
    if (ws_size >= (size_t)WS_NEED) {
        unsigned short* wt = (unsigned short*)d_ws;
        unsigned short* xt = wt + WT_ELEMS;
        static int attr_done = 0;
        if (!attr_done) {
            hipFuncSetAttribute((const void*)gemm8,
                                hipFuncAttributeMaxDynamicSharedMemorySize, 131072);
            attr_done = 1;
        }
        prep_w<<<288, 256, 0, stream>>>(w, wt);
        prep_x<<<32 * 58, 256, 0, stream>>>(x, xt);
        gemm8<<<392, 512, 131072, stream>>>(wt, xt, out);
    } else {
        conv_naive<<<N_TOT, 256, 0, stream>>>(x, w, out);
    }
}